// Round 6
// baseline (103.159 us; speedup 1.0000x reference)
//
#include <hip/hip_runtime.h>

namespace {
constexpr int Bc  = 4;
constexpr int Lc  = 4096;
constexpr int Dc  = 2048;
constexpr int Gc  = 32;
constexpr int GSc = 64;
constexpr int SC  = 512;                 // timesteps per sub-chunk
constexpr int NSC = Lc / SC;             // 8 sub-chunks
constexpr float EPSc = 1e-5f;
constexpr long long NY = (long long)Bc * Lc * Dc;   // 33,554,432
typedef float vfloat4 __attribute__((ext_vector_type(4)));
#define SCOPE_AGENT __HIP_MEMORY_SCOPE_AGENT
}

// Re-initialize the carry-chain state every launch (ws is not re-poisoned
// between graph replays; determinism requires explicit init).
__global__ void kInit(int* __restrict__ seq, double* __restrict__ carry) {
    int t = threadIdx.x;                 // 128 threads, one per bg
    seq[t] = 0;
    carry[t * 3 + 0] = 0.0;
    carry[t * 3 + 1] = 0.0;
    carry[t * 3 + 2] = 0.0;
}

// Single-pass timestep-norm. Grid = 256 blocks: block (bg, p) owns sub-chunks
// {p, p+2, p+4, p+6} of its (b,g) column. The x-slice lives in registers from
// load to normalize (x is read from HBM exactly ONCE). The running Welford
// carry (S1, S2, count in fp64) ping-pongs between the bg's two blocks via an
// acquire/release seq flag in global memory.
__global__ __launch_bounds__(256, 2) void kMain(
        const float* __restrict__ x,
        const int* __restrict__ prev_count,
        const float* __restrict__ prev_mean,
        const float* __restrict__ prev_var,
        const int* __restrict__ mask,
        const float* __restrict__ w,
        const float* __restrict__ bias,
        float* __restrict__ y,
        float* __restrict__ out_count,
        float* __restrict__ out_mean,
        float* __restrict__ out_var,
        int* __restrict__ seq,
        double* __restrict__ carry) {
    const int blk = blockIdx.x;
    const int bg = blk >> 1, p = blk & 1;
    const int b = bg >> 5, g = bg & (Gc - 1);
    const int tid = threadIdx.x;
    const int r16 = tid >> 4, col4 = tid & 15;

    __shared__ float  sm[SC];
    __shared__ float  smean[SC], srstd[SC];
    __shared__ double s1[256], s2[256];
    __shared__ int    scnt[256];
    __shared__ double cLDS[3];

    const double c0    = (double)prev_count[b];
    const double mean0 = (double)prev_mean[bg];
    const double M2_0  = (double)prev_var[bg] * fmax(c0, 1.0);
    const float c0f = (float)c0, mean0f = (float)mean0, M2_0f = (float)M2_0;

    const float4 wv  = *reinterpret_cast<const float4*>(w + g * GSc + col4 * 4);
    const float4 bvv = *reinterpret_cast<const float4*>(bias + g * GSc + col4 * 4);

    for (int k = 0; k < NSC / 2; ++k) {
        const int sc = k * 2 + p;
        const int tbase = sc * SC;
        const long long xbase = ((long long)b * Lc + tbase) * Dc + (long long)g * GSc + col4 * 4;

        // ---- load slice into registers (the only HBM read of x) ----
        float4 xa[32];
        #pragma unroll
        for (int it = 0; it < 32; ++it) {
            xa[it] = *reinterpret_cast<const float4*>(x + xbase + (long long)(it * 16 + r16) * Dc);
        }

        // ---- group means via 16-lane segmented shfl reduce ----
        #pragma unroll
        for (int it = 0; it < 32; ++it) {
            float s = xa[it].x + xa[it].y + xa[it].z + xa[it].w;
            s += __shfl_xor(s, 1);
            s += __shfl_xor(s, 2);
            s += __shfl_xor(s, 4);
            s += __shfl_xor(s, 8);
            if (col4 == 0) sm[it * 16 + r16] = s * (1.0f / GSc);
        }
        __syncthreads();

        // ---- masked fp64 prefix scan over the 512 means (2 elems/thread) ----
        const int* mrow = mask + (long long)b * Lc + tbase;
        float v0 = sm[tid * 2], v1 = sm[tid * 2 + 1];
        int q0 = mrow[tid * 2], q1 = mrow[tid * 2 + 1];
        double ls1 = 0.0, ls2 = 0.0; int lc = 0;
        if (q0) { ls1 += v0; ls2 += (double)v0 * v0; ++lc; }
        if (q1) { ls1 += v1; ls2 += (double)v1 * v1; ++lc; }
        s1[tid] = ls1; s2[tid] = ls2; scnt[tid] = lc;
        __syncthreads();
        for (int off = 1; off < 256; off <<= 1) {
            double a1 = 0.0, a2 = 0.0; int ac = 0;
            if (tid >= off) { a1 = s1[tid - off]; a2 = s2[tid - off]; ac = scnt[tid - off]; }
            __syncthreads();
            s1[tid] += a1; s2[tid] += a2; scnt[tid] += ac;
            __syncthreads();
        }
        const double ex1 = s1[tid] - ls1, ex2 = s2[tid] - ls2;
        const int exc = scnt[tid] - lc;

        // ---- acquire carry, publish updated carry ASAP (tid 0) ----
        if (tid == 0) {
            while (__hip_atomic_load(&seq[bg], __ATOMIC_ACQUIRE, SCOPE_AGENT) < sc) {
                __builtin_amdgcn_s_sleep(2);
            }
            double c1   = __hip_atomic_load(&carry[bg * 3 + 0], __ATOMIC_RELAXED, SCOPE_AGENT);
            double c2   = __hip_atomic_load(&carry[bg * 3 + 1], __ATOMIC_RELAXED, SCOPE_AGENT);
            double ccnt = __hip_atomic_load(&carry[bg * 3 + 2], __ATOMIC_RELAXED, SCOPE_AGENT);
            cLDS[0] = c1; cLDS[1] = c2; cLDS[2] = ccnt;
            const double n1 = c1 + s1[255], n2 = c2 + s2[255], nc = ccnt + (double)scnt[255];
            __hip_atomic_store(&carry[bg * 3 + 0], n1, __ATOMIC_RELAXED, SCOPE_AGENT);
            __hip_atomic_store(&carry[bg * 3 + 1], n2, __ATOMIC_RELAXED, SCOPE_AGENT);
            __hip_atomic_store(&carry[bg * 3 + 2], nc, __ATOMIC_RELAXED, SCOPE_AGENT);
            __hip_atomic_store(&seq[bg], sc + 1, __ATOMIC_RELEASE, SCOPE_AGENT);
            if (sc == NSC - 1) {
                // final carry outputs in fp64 (reference-equivalent Chan merge)
                double ctot = c0 + nc, csafe = fmax(ctot, 1.0);
                double meanF = (c0 * mean0 + n1) / csafe;
                double M2 = M2_0;
                if (nc > 0.0) {
                    M2 += n2 - n1 * n1 / nc;
                    double dd = n1 / nc - mean0;
                    M2 += dd * dd * c0 * nc / csafe;
                }
                if (g == 0) out_count[b] = (float)ctot;  // read back as float32
                out_mean[bg] = (float)meanF;
                out_var[bg]  = (float)(M2 / csafe);
            }
        }
        __syncthreads();

        // ---- per-timestep finalize (fp32 rcp/rsq), 2 rows per thread ----
        double run1 = cLDS[0] + ex1, run2 = cLDS[1] + ex2, runc = cLDS[2] + (double)exc;
        #pragma unroll
        for (int e = 0; e < 2; ++e) {
            float vv = e ? v1 : v0;
            int qq = e ? q1 : q0;
            if (qq) { run1 += vv; run2 += (double)vv * vv; runc += 1.0; }
            float run1f = (float)run1, run2f = (float)run2, cv = (float)runc;
            float ctot = c0f + cv, csafe = fmaxf(ctot, 1.0f);
            float invcs = __builtin_amdgcn_rcpf(csafe);
            float meanT = fmaf(c0f, mean0f, run1f) * invcs;
            float M2 = M2_0f;
            if (runc > 0.0) {
                float invcv = __builtin_amdgcn_rcpf(cv);
                M2 += run2f - run1f * run1f * invcv;
                float dd = run1f * invcv - mean0f;
                M2 += dd * dd * c0f * cv * invcs;
            }
            float varT = M2 * invcs;
            smean[tid * 2 + e] = meanT;
            srstd[tid * 2 + e] = __builtin_amdgcn_rsqf(varT + EPSc);
        }
        __syncthreads();

        // ---- normalize from registers, NT store ----
        #pragma unroll
        for (int it = 0; it < 32; ++it) {
            const int r = it * 16 + r16;
            const float mean = smean[r];
            const float rstd = srstd[r];
            vfloat4 yv;
            yv.x = (xa[it].x - mean) * rstd * wv.x + bvv.x;
            yv.y = (xa[it].y - mean) * rstd * wv.y + bvv.y;
            yv.z = (xa[it].z - mean) * rstd * wv.z + bvv.z;
            yv.w = (xa[it].w - mean) * rstd * wv.w + bvv.w;
            __builtin_nontemporal_store(
                yv, reinterpret_cast<vfloat4*>(y + xbase + (long long)(it * 16 + r16) * Dc));
        }
        __syncthreads();   // protect sm/smean reuse next iteration
    }
}

extern "C" void kernel_launch(void* const* d_in, const int* in_sizes, int n_in,
                              void* d_out, int out_size, void* d_ws, size_t ws_size,
                              hipStream_t stream) {
    const float* x         = (const float*)d_in[0];
    const int* prev_count  = (const int*)d_in[1];
    const float* prev_mean = (const float*)d_in[2];
    const float* prev_var  = (const float*)d_in[3];
    const int* mask        = (const int*)d_in[4];   // bool -> int32 per harness
    const float* weight    = (const float*)d_in[5];
    const float* bias      = (const float*)d_in[6];

    float* out       = (float*)d_out;
    float* y         = out;
    float* out_count = out + NY;
    float* out_mean  = out_count + Bc;
    float* out_var   = out_mean + (long long)Bc * Gc;

    double* carry = (double*)d_ws;                       // 128 * 3 doubles
    int* seq      = (int*)((char*)d_ws + 128 * 3 * sizeof(double));

    kInit<<<1, 128, 0, stream>>>(seq, carry);
    kMain<<<Bc * Gc * 2, 256, 0, stream>>>(x, prev_count, prev_mean, prev_var,
                                           mask, weight, bias, y,
                                           out_count, out_mean, out_var, seq, carry);
}